// Round 11
// baseline (228.136 us; speedup 1.0000x reference)
//
#include <hip/hip_runtime.h>

constexpr int NB = 10, H = 128;
constexpr int M = 64 * 1024;             // B*A rows
constexpr long SL = (long)M * H;         // elems per [M,H] matrix

typedef __attribute__((ext_vector_type(8))) short s16x8;
typedef __attribute__((ext_vector_type(4))) float f32x4;

__device__ __forceinline__ ushort f2b(float f) {
    union { float f; uint u; } v; v.f = f;
    uint u = v.u;
    uint r = u + 0x7fffu + ((u >> 16) & 1u);
    return (ushort)(r >> 16);
}
__device__ __forceinline__ float b2f(ushort u) {
    union { uint u; float f; } v; v.u = ((uint)u) << 16; return v.f;
}

// XCD-chunked bijective swizzle (sub-grid % 8 == 0)
__device__ __forceinline__ int swz(int bid, int cpx) {
    return (bid & 7) * cpx + (bid >> 3);
}

// ---------------------------------------------------------------------------
// GEMM body: wave owns 32 cols (8 weight frags = 32 VGPR, truly resident),
// walks 4 row-tiles.  FLAGS: 8=KOUT (v *= b2f(FN)*nmask), 16=OF32
// ---------------------------------------------------------------------------
template<int NC, int FLAGS>
__device__ __forceinline__ void gemm_body(
    int tg, const ushort* __restrict__ Abf, const ushort* __restrict__ WT,
    const ushort* __restrict__ FNb, const float* __restrict__ nmask,
    float* __restrict__ Cf, ushort* __restrict__ Cb)
{
    constexpr bool KOUT = FLAGS & 8, OF32 = FLAGS & 16;
    constexpr int K = NC * 32;
    const int lane = threadIdx.x & 63, wid = threadIdx.x >> 6;
    const int l15 = lane & 15, g = lane >> 4;

    s16x8 w[2][NC];
    #pragma unroll
    for (int ct = 0; ct < 2; ++ct)
        #pragma unroll
        for (int kc = 0; kc < NC; ++kc)
            w[ct][kc] = *(const s16x8*)(WT + (size_t)((2 * wid + ct) * 16 + l15) * K + kc * 32 + g * 8);

    #pragma unroll
    for (int i = 0; i < 4; ++i) {
        const int m0 = (tg * 4 + i) * 16;
        s16x8 ac[NC];
        #pragma unroll
        for (int kc = 0; kc < NC; ++kc)
            ac[kc] = *(const s16x8*)(Abf + (size_t)(m0 + l15) * K + kc * 32 + g * 8);

        f32x4 acc[2];
        #pragma unroll
        for (int ct = 0; ct < 2; ++ct) acc[ct] = (f32x4){0.f, 0.f, 0.f, 0.f};
        #pragma unroll
        for (int kc = 0; kc < NC; ++kc)
            #pragma unroll
            for (int ct = 0; ct < 2; ++ct)
                acc[ct] = __builtin_amdgcn_mfma_f32_16x16x32_bf16(ac[kc], w[ct][kc], acc[ct], 0, 0, 0);

        #pragma unroll
        for (int ct = 0; ct < 2; ++ct) {
            const int col = (2 * wid + ct) * 16 + l15;
            #pragma unroll
            for (int r = 0; r < 4; ++r) {
                const int m = m0 + 4 * g + r;
                const size_t o = (size_t)m * H + col;
                float v = acc[ct][r];
                if constexpr (KOUT) v = v * b2f(FNb[o]) * nmask[m];
                if constexpr (OF32) Cf[o] = v; else Cb[o] = f2b(v);
            }
        }
    }
}

// ---------------------------------------------------------------------------
// Composed-U1 body v2: out = AF@Wu1a + SATOM@Wc + FBS8@W2c   (K=288)
// Wave owns ONE coltile (16 cols): 9 weight frags = 36 VGPR, genuinely
// register-resident (total ~88 VGPR < 128 cap) -> weight loads hoisted out
// of the row-tile loop.  gid in [0,8192): c0 = gid&7, rowgroup = gid>>3.
// ---------------------------------------------------------------------------
template<bool OF32>
__device__ __forceinline__ void u1f_body(
    int gid, const ushort* __restrict__ AF, const ushort* __restrict__ SATOM,
    const ushort* __restrict__ FBSb, const ushort* __restrict__ WT,
    float* __restrict__ Cf, ushort* __restrict__ Cb)
{
    const int lane = threadIdx.x & 63;
    const int l15 = lane & 15, g = lane >> 4;
    const int c0 = gid & 7;
    const int rg = gid >> 3;

    s16x8 w[9];
    #pragma unroll
    for (int kc = 0; kc < 9; ++kc)
        w[kc] = *(const s16x8*)(WT + (size_t)(c0 * 16 + l15) * 288 + kc * 32 + g * 8);

    #pragma unroll
    for (int i = 0; i < 4; ++i) {
        const int m0 = (rg * 4 + i) * 16;
        const size_t rb = (size_t)(m0 + l15) * H + g * 8;
        s16x8 ac[9];
        #pragma unroll
        for (int kc = 0; kc < 4; ++kc) {
            ac[kc]     = *(const s16x8*)(AF    + rb + kc * 32);
            ac[kc + 4] = *(const s16x8*)(SATOM + rb + kc * 32);
        }
        ac[8] = (s16x8){0,0,0,0,0,0,0,0};
        if (g == 0) ac[8] = *(const s16x8*)(FBSb + (size_t)(m0 + l15) * 8);

        f32x4 acc = (f32x4){0.f, 0.f, 0.f, 0.f};
        #pragma unroll
        for (int kc = 0; kc < 9; ++kc)
            acc = __builtin_amdgcn_mfma_f32_16x16x32_bf16(ac[kc], w[kc], acc, 0, 0, 0);

        const int col = c0 * 16 + l15;
        #pragma unroll
        for (int r = 0; r < 4; ++r) {
            const size_t o = (size_t)(m0 + 4 * g + r) * H + col;
            if constexpr (OF32) Cf[o] = acc[r]; else Cb[o] = f2b(acc[r]);
        }
    }
}

template<int NC, int FLAGS>
__global__ __launch_bounds__(256, 4) void gemm_af(
    const ushort* __restrict__ Abf, const ushort* __restrict__ WT,
    const ushort* __restrict__ FNb, const float* __restrict__ nmask,
    float* __restrict__ Cf, ushort* __restrict__ Cb)
{
    gemm_body<NC, FLAGS>(swz(blockIdx.x, 128), Abf, WT, FNb, nmask, Cf, Cb);
}

template<bool OF32>
__global__ __launch_bounds__(256, 4) void u1f(
    const ushort* __restrict__ AF, const ushort* __restrict__ SATOM,
    const ushort* __restrict__ FBSb, const ushort* __restrict__ WT,
    float* __restrict__ Cf, ushort* __restrict__ Cb)
{
    const int gid = swz(blockIdx.x, 256) * 4 + (threadIdx.x >> 6);
    u1f_body<OF32>(gid, AF, SATOM, FBSb, WT, Cf, Cb);
}

// final2: [0,2048): atom_features = [AF|SATl|FBS]@WTu1f -> out1 (f32)
//         [2048,3072): kernel = (AF@Wslf)*FNEI*nmask   -> out0 (f32)
__global__ __launch_bounds__(256, 4) void final2(
    const ushort* __restrict__ AF, const ushort* __restrict__ SATl,
    const ushort* __restrict__ FBSb, const ushort* __restrict__ WTu1f,
    const ushort* __restrict__ WTslf, const ushort* __restrict__ FNEIb,
    const float* __restrict__ nmask, float* __restrict__ out1,
    float* __restrict__ out0)
{
    if (blockIdx.x < 2048) {
        const int gid = swz(blockIdx.x, 256) * 4 + (threadIdx.x >> 6);
        u1f_body<true>(gid, AF, SATl, FBSb, WTu1f, out1, nullptr);
    } else {
        gemm_body<4, 8 | 16>(swz(blockIdx.x - 2048, 128), AF, WTslf, FNEIb,
                             nmask, out0, nullptr);
    }
}

// ---------------------------------------------------------------------------
// SATOM gather body: SATOM[m][:] = sum_{nb<nnb} AF[b, ag[m,nb]][:]  (bf16)
// ---------------------------------------------------------------------------
__device__ __forceinline__ void satom_body(
    int bid, const ushort* __restrict__ AF, const int* __restrict__ ag,
    const int* __restrict__ nn, ushort* __restrict__ SATOM)
{
    const int m  = bid * 16 + (threadIdx.x >> 4);
    const int c8 = (threadIdx.x & 15) * 8;
    const int b  = m >> 10;
    const int nnb = nn[m];
    const ushort* AFb = AF + ((size_t)b << 10) * H + c8;
    const int* agm = ag + (size_t)m * NB;

    int2 iv0 = *(const int2*)(agm + 0);
    int2 iv1 = *(const int2*)(agm + 2);
    int2 iv2 = *(const int2*)(agm + 4);
    int2 iv3 = *(const int2*)(agm + 6);
    int2 iv4 = *(const int2*)(agm + 8);

    float sacc[8];
    #pragma unroll
    for (int i = 0; i < 8; ++i) sacc[i] = 0.f;

    #define GS_STEP(nb, ia)                                              \
    if ((nb) < nnb) {                                                    \
        s16x8 av = *(const s16x8*)(AFb + (size_t)(ia) * H);              \
        _Pragma("unroll")                                                \
        for (int i = 0; i < 8; ++i) sacc[i] += b2f((ushort)av[i]);       \
    }
    GS_STEP(0, iv0.x) GS_STEP(1, iv0.y)
    GS_STEP(2, iv1.x) GS_STEP(3, iv1.y)
    GS_STEP(4, iv2.x) GS_STEP(5, iv2.y)
    GS_STEP(6, iv3.x) GS_STEP(7, iv3.y)
    GS_STEP(8, iv4.x) GS_STEP(9, iv4.y)
    #undef GS_STEP

    s16x8 so;
    #pragma unroll
    for (int i = 0; i < 8; ++i) so[i] = (short)f2b(sacc[i]);
    *(s16x8*)(SATOM + (size_t)m * H + c8) = so;
}

__global__ __launch_bounds__(256, 8) void gather_satom(
    const ushort* __restrict__ AF, const int* __restrict__ ag,
    const int* __restrict__ nn, ushort* __restrict__ SATOM)
{
    satom_body(swz(blockIdx.x, 512), AF, ag, nn, SATOM);
}

// ---------------------------------------------------------------------------
// K1: [0,4096): SATOM gather (depth 0)  |  [4096,12288): HB = bond @ Wnb
// ---------------------------------------------------------------------------
__global__ __launch_bounds__(256, 8) void k1_sat_hb(
    const ushort* __restrict__ AF, const int* __restrict__ ag,
    const int* __restrict__ nn, const float* __restrict__ bond,
    const float* __restrict__ Wnb, ushort* __restrict__ SATOM,
    ushort* __restrict__ HB)
{
    if (blockIdx.x < 4096) {
        satom_body(swz(blockIdx.x, 512), AF, ag, nn, SATOM);
    } else {
        const int t = (blockIdx.x - 4096) * 256 + threadIdx.x;   // B*E*16
        const int r = t >> 4, c8 = (t & 15) * 8;
        const float* fb = bond + (size_t)r * 6;
        const float2 f01 = *(const float2*)fb;
        const float2 f23 = *(const float2*)(fb + 2);
        const float2 f45 = *(const float2*)(fb + 4);
        s16x8 o;
        #pragma unroll
        for (int i = 0; i < 8; ++i) {
            const int c = c8 + i;
            const float v = f01.x * Wnb[0 * H + c] + f01.y * Wnb[1 * H + c]
                          + f23.x * Wnb[2 * H + c] + f23.y * Wnb[3 * H + c]
                          + f45.x * Wnb[4 * H + c] + f45.y * Wnb[5 * H + c];
            o[i] = (short)f2b(v);
        }
        *(s16x8*)(HB + (size_t)r * H + c8) = o;
    }
}

// ---------------------------------------------------------------------------
// Last-depth gather: SATOM and FNEI = sum_nb ATW[ag]*HB[bg]  (both bf16 out)
// ---------------------------------------------------------------------------
__global__ __launch_bounds__(256, 4) void gather_last(
    const ushort* __restrict__ AF, const ushort* __restrict__ ATW,
    const ushort* __restrict__ HB, const int* __restrict__ ag,
    const int* __restrict__ bg, const int* __restrict__ nn,
    ushort* __restrict__ SATOM, ushort* __restrict__ FNEIb)
{
    const int bid = swz(blockIdx.x, 512);
    const int m  = bid * 16 + (threadIdx.x >> 4);
    const int c8 = (threadIdx.x & 15) * 8;
    const int b  = m >> 10;
    const int nnb = nn[m];
    const ushort* AFb  = AF  + ((size_t)b << 10) * H + c8;
    const ushort* ATWb = ATW + ((size_t)b << 10) * H + c8;
    const ushort* HBb  = HB  + ((size_t)b << 11) * H + c8;   // E = 2048
    const int* agm = ag + (size_t)m * NB;
    const int* bgm = bg + (size_t)m * NB;

    int2 ia0 = *(const int2*)(agm + 0), ib0 = *(const int2*)(bgm + 0);
    int2 ia1 = *(const int2*)(agm + 2), ib1 = *(const int2*)(bgm + 2);
    int2 ia2 = *(const int2*)(agm + 4), ib2 = *(const int2*)(bgm + 4);
    int2 ia3 = *(const int2*)(agm + 6), ib3 = *(const int2*)(bgm + 6);
    int2 ia4 = *(const int2*)(agm + 8), ib4 = *(const int2*)(bgm + 8);

    float sacc[8], facc[8];
    #pragma unroll
    for (int i = 0; i < 8; ++i) { sacc[i] = 0.f; facc[i] = 0.f; }

    #define GL_STEP(nb, ia, ib)                                          \
    if ((nb) < nnb) {                                                    \
        s16x8 av = *(const s16x8*)(AFb  + (size_t)(ia) * H);             \
        s16x8 tv = *(const s16x8*)(ATWb + (size_t)(ia) * H);             \
        s16x8 hv = *(const s16x8*)(HBb  + (size_t)(ib) * H);             \
        _Pragma("unroll")                                                \
        for (int i = 0; i < 8; ++i) {                                    \
            sacc[i] += b2f((ushort)av[i]);                               \
            facc[i] += b2f((ushort)tv[i]) * b2f((ushort)hv[i]);          \
        }                                                                \
    }
    GL_STEP(0, ia0.x, ib0.x) GL_STEP(1, ia0.y, ib0.y)
    GL_STEP(2, ia1.x, ib1.x) GL_STEP(3, ia1.y, ib1.y)
    GL_STEP(4, ia2.x, ib2.x) GL_STEP(5, ia2.y, ib2.y)
    GL_STEP(6, ia3.x, ib3.x) GL_STEP(7, ia3.y, ib3.y)
    GL_STEP(8, ia4.x, ib4.x) GL_STEP(9, ia4.y, ib4.y)
    #undef GL_STEP

    s16x8 so, fo;
    #pragma unroll
    for (int i = 0; i < 8; ++i) { so[i] = (short)f2b(sacc[i]); fo[i] = (short)f2b(facc[i]); }
    *(s16x8*)(SATOM + (size_t)m * H + c8) = so;
    *(s16x8*)(FNEIb + (size_t)m * H + c8) = fo;
}

// ---------------------------------------------------------------------------
// FA GEMM body reading input_atom f32 directly (K=96 logical, cols>=82 zero)
// ---------------------------------------------------------------------------
__device__ __forceinline__ void fa_body(
    int tg, const float* __restrict__ ia, const float* __restrict__ Wa,
    ushort* __restrict__ Cb)
{
    const int lane = threadIdx.x & 63, wid = threadIdx.x >> 6;
    const int l15 = lane & 15, g = lane >> 4;

    s16x8 w[2][3];
    #pragma unroll
    for (int ct = 0; ct < 2; ++ct) {
        const int n = (2 * wid + ct) * 16 + l15;
        #pragma unroll
        for (int kc = 0; kc < 3; ++kc) {
            s16x8 wv;
            #pragma unroll
            for (int i = 0; i < 8; ++i) {
                const int k = kc * 32 + g * 8 + i;
                wv[i] = (short)(k < 82 ? f2b(Wa[k * H + n]) : 0);
            }
            w[ct][kc] = wv;
        }
    }

    #pragma unroll
    for (int t = 0; t < 4; ++t) {
        const int m0 = (tg * 4 + t) * 16;
        const float* row = ia + (size_t)(m0 + l15) * 82;
        s16x8 a[3];
        #pragma unroll
        for (int kc = 0; kc < 3; ++kc) {
            #pragma unroll
            for (int p = 0; p < 4; ++p) {
                const int k = kc * 32 + g * 8 + 2 * p;     // even; boundary 82 even
                float2 v = (k < 82) ? *(const float2*)(row + k)
                                    : make_float2(0.f, 0.f);
                a[kc][2 * p]     = (short)f2b(v.x);
                a[kc][2 * p + 1] = (short)f2b(v.y);
            }
        }
        f32x4 acc[2];
        #pragma unroll
        for (int ct = 0; ct < 2; ++ct) acc[ct] = (f32x4){0.f, 0.f, 0.f, 0.f};
        #pragma unroll
        for (int kc = 0; kc < 3; ++kc)
            #pragma unroll
            for (int ct = 0; ct < 2; ++ct)
                acc[ct] = __builtin_amdgcn_mfma_f32_16x16x32_bf16(a[kc], w[ct][kc], acc[ct], 0, 0, 0);
        #pragma unroll
        for (int ct = 0; ct < 2; ++ct) {
            const int col = (2 * wid + ct) * 16 + l15;
            #pragma unroll
            for (int r = 0; r < 4; ++r)
                Cb[(size_t)(m0 + 4 * g + r) * H + col] = f2b(acc[ct][r]);
        }
    }
}

// ---------------------------------------------------------------------------
// K0: block-range-split {FA gemm | weights compose | FBS8}
//  [0,1024): FA  [1024,1296): weights  [1296,1552): FBS
//  WTs layout: WTna[128][128] | WTslf[128][128] | WTu1f[128][288]
// ---------------------------------------------------------------------------
__global__ __launch_bounds__(256, 4) void k0_prep_fa(
    const float* __restrict__ ia, const float* __restrict__ Wa,
    const float* __restrict__ Wna, const float* __restrict__ Ws,
    const float* __restrict__ Wu2, const float* __restrict__ bu2,
    const float* __restrict__ Wu1, const float* __restrict__ bu1,
    const float* __restrict__ bond, const int* __restrict__ bg,
    const int* __restrict__ nn,
    ushort* __restrict__ AF0, ushort* __restrict__ WTs,
    ushort* __restrict__ FBSb)
{
    const int bid = blockIdx.x;
    if (bid < 1024) {
        fa_body(swz(bid, 128), ia, Wa, AF0);
    } else if (bid < 1296) {
        int t = (bid - 1024) * 256 + threadIdx.x;
        const int tid = t;
        if (t < 128 * 128) { int n = t / 128, k = t % 128;
            WTs[tid] = f2b(Wna[k * H + n]); return; }
        t -= 128 * 128;
        if (t < 128 * 128) { int n = t / 128, k = t % 128;
            WTs[tid] = f2b(Ws[k * H + n]); return; }
        t -= 128 * 128;
        {
            const int n = t / 288, k = t % 288;
            float v = 0.f;
            if (k < 128) {
                v = Wu1[k * H + n];
            } else if (k < 256) {
                const int kk = k - 128;
                float s = 0.f;
                for (int j = 0; j < 128; ++j) s += Wu2[kk * H + j] * Wu1[(128 + j) * H + n];
                v = s;
            } else {
                const int j = k - 256;
                if (j < 6) {
                    float s = 0.f;
                    for (int q = 0; q < 128; ++q) s += Wu2[(128 + j) * H + q] * Wu1[(128 + q) * H + n];
                    v = s;
                } else if (j == 6) {
                    float s = 0.f;
                    for (int q = 0; q < 128; ++q) s += bu2[q] * Wu1[(128 + q) * H + n];
                    v = s;
                } else if (j == 7) {
                    v = bu1[n];
                }
            }
            WTs[tid] = f2b(v);
            return;
        }
    } else {
        // FBS8[m][8] = bf16[ sum_nb bond[bg[m,nb]][0..5], num_nbs, 1 ]
        const int m = (bid - 1296) * 256 + threadIdx.x;
        const int b = m >> 10;
        const int nnb = nn[m];
        float s[6] = {0,0,0,0,0,0};
        for (int nb = 0; nb < nnb; ++nb) {
            const int ib = bg[m * NB + nb];
            const float* fb = bond + ((size_t)(b << 11) + (size_t)ib) * 6;
            #pragma unroll
            for (int j = 0; j < 6; ++j) s[j] += fb[j];
        }
        s16x8 o;
        #pragma unroll
        for (int j = 0; j < 6; ++j) o[j] = (short)f2b(s[j]);
        o[6] = (short)f2b((float)nnb);
        o[7] = (short)f2b(1.0f);
        *(s16x8*)(FBSb + (size_t)m * 8) = o;
    }
}

// ---------------------------------------------------------------------------
extern "C" void kernel_launch(void* const* d_in, const int* in_sizes, int n_in,
                              void* d_out, int out_size, void* d_ws, size_t ws_size,
                              hipStream_t stream)
{
    (void)in_sizes; (void)n_in; (void)out_size; (void)ws_size;

    const float* input_atom = (const float*)d_in[0];
    const float* input_bond = (const float*)d_in[1];
    const int*   atom_graph = (const int*)d_in[2];
    const int*   bond_graph = (const int*)d_in[3];
    const int*   num_nbs    = (const int*)d_in[4];
    const float* node_mask  = (const float*)d_in[5];
    const float* W_atom     = (const float*)d_in[6];
    const float* W_nei_atom = (const float*)d_in[7];
    const float* W_nei_bond = (const float*)d_in[8];
    const float* W_self     = (const float*)d_in[9];
    const float* W_U2       = (const float*)d_in[10];
    const float* b_U2       = (const float*)d_in[11];
    const float* W_U1       = (const float*)d_in[12];
    const float* b_U1       = (const float*)d_in[13];

    char* ws = (char*)d_ws;
    const size_t MB = 1024 * 1024;
    ushort* AF0   = (ushort*)(ws);               // [0,16) MB
    ushort* AF1   = (ushort*)(ws + 16 * MB);     // [16,32) MB (FNEI at last depth)
    ushort* SATw  = (ushort*)(ws + 32 * MB);     // [32,48) MB (ATW at last depth)
    ushort* ATW   = SATw;
    ushort* HB    = (ushort*)(ws + 64 * MB);     // [64,96) MB
    ushort* SATl  = (ushort*)(ws + 96 * MB);     // [96,112) MB
    ushort* FBSb  = (ushort*)(ws + 112 * MB);    // 1 MB
    ushort* WTs_  = (ushort*)(ws + 113 * MB);    // ~140 KB

    ushort* WTna  = WTs_;                        // [128][128]
    ushort* WTslf = WTna  + 128 * 128;           // [128][128]
    ushort* WTu1f = WTslf + 128 * 128;           // [128][288]

    float*  out0  = (float*)d_out;               // kernel [M][128] f32
    float*  out1  = out0 + SL;                   // atom_features [M][128] f32
    ushort* FNEIb = AF1;                         // last-depth FNEI scratch

    // K0: FA gemm || weights compose || FBS
    k0_prep_fa<<<1552, 256, 0, stream>>>(input_atom, W_atom, W_nei_atom,
                                         W_self, W_U2, b_U2, W_U1, b_U1,
                                         input_bond, bond_graph, num_nbs,
                                         AF0, WTs_, FBSb);

    // depth 0: SATOM gather || HB precompute (independent; fills idle BW)
    k1_sat_hb<<<12288, 256, 0, stream>>>(AF0, atom_graph, num_nbs,
                                         input_bond, W_nei_bond, SATw, HB);
    u1f<false><<<2048, 256, 0, stream>>>(AF0, SATw, FBSb, WTu1f, nullptr, AF1);
    // depth 1
    gather_satom<<<4096, 256, 0, stream>>>(AF1, atom_graph, num_nbs, SATw);
    u1f<false><<<2048, 256, 0, stream>>>(AF1, SATw, FBSb, WTu1f, nullptr, AF0);

    // ---- last depth (AF = AF0; AF1 dead -> FNEI scratch; SATw -> ATW) ----
    gemm_af<4, 0><<<1024, 256, 0, stream>>>(AF0, WTna, nullptr, nullptr,
                                            nullptr, ATW);
    gather_last<<<4096, 256, 0, stream>>>(AF0, ATW, HB, atom_graph, bond_graph,
                                          num_nbs, SATl, FNEIb);
    // atom_features -> out1 (f32)  ||  kernel -> out0 (f32)
    final2<<<3072, 256, 0, stream>>>(AF0, SATl, FBSb, WTu1f, WTslf, FNEIb,
                                     node_mask, out1, out0);
}

// Round 12
// 202.355 us; speedup vs baseline: 1.1274x; 1.1274x over previous
//
#include <hip/hip_runtime.h>

constexpr int NB = 10, H = 128;
constexpr int M = 64 * 1024;             // B*A rows
constexpr long SL = (long)M * H;         // elems per [M,H] matrix
constexpr int WPAD = 290;                // padded LDS row stride (dword 145 ≡ 17 mod 32)

typedef __attribute__((ext_vector_type(8))) short s16x8;
typedef __attribute__((ext_vector_type(4))) float f32x4;

__device__ __forceinline__ ushort f2b(float f) {
    union { float f; uint u; } v; v.f = f;
    uint u = v.u;
    uint r = u + 0x7fffu + ((u >> 16) & 1u);
    return (ushort)(r >> 16);
}
__device__ __forceinline__ float b2f(ushort u) {
    union { uint u; float f; } v; v.u = ((uint)u) << 16; return v.f;
}

// XCD-chunked bijective swizzle (sub-grid % 8 == 0)
__device__ __forceinline__ int swz(int bid, int cpx) {
    return (bid & 7) * cpx + (bid >> 3);
}

// ---------------------------------------------------------------------------
// GEMM body (K=NC*32<=128): wave owns 32 cols, weights genuinely VGPR-resident
// (w[2][4]=32 VGPR fits the 64-reg tier).  FLAGS: 8=KOUT, 16=OF32
// ---------------------------------------------------------------------------
template<int NC, int FLAGS>
__device__ __forceinline__ void gemm_body(
    int tg, const ushort* __restrict__ Abf, const ushort* __restrict__ WT,
    const ushort* __restrict__ FNb, const float* __restrict__ nmask,
    float* __restrict__ Cf, ushort* __restrict__ Cb)
{
    constexpr bool KOUT = FLAGS & 8, OF32 = FLAGS & 16;
    constexpr int K = NC * 32;
    const int lane = threadIdx.x & 63, wid = threadIdx.x >> 6;
    const int l15 = lane & 15, g = lane >> 4;

    s16x8 w[2][NC];
    #pragma unroll
    for (int ct = 0; ct < 2; ++ct)
        #pragma unroll
        for (int kc = 0; kc < NC; ++kc)
            w[ct][kc] = *(const s16x8*)(WT + (size_t)((2 * wid + ct) * 16 + l15) * K + kc * 32 + g * 8);

    #pragma unroll
    for (int i = 0; i < 4; ++i) {
        const int m0 = (tg * 4 + i) * 16;
        s16x8 ac[NC];
        #pragma unroll
        for (int kc = 0; kc < NC; ++kc)
            ac[kc] = *(const s16x8*)(Abf + (size_t)(m0 + l15) * K + kc * 32 + g * 8);

        f32x4 acc[2];
        #pragma unroll
        for (int ct = 0; ct < 2; ++ct) acc[ct] = (f32x4){0.f, 0.f, 0.f, 0.f};
        #pragma unroll
        for (int kc = 0; kc < NC; ++kc)
            #pragma unroll
            for (int ct = 0; ct < 2; ++ct)
                acc[ct] = __builtin_amdgcn_mfma_f32_16x16x32_bf16(ac[kc], w[ct][kc], acc[ct], 0, 0, 0);

        #pragma unroll
        for (int ct = 0; ct < 2; ++ct) {
            const int col = (2 * wid + ct) * 16 + l15;
            #pragma unroll
            for (int r = 0; r < 4; ++r) {
                const int m = m0 + 4 * g + r;
                const size_t o = (size_t)m * H + col;
                float v = acc[ct][r];
                if constexpr (KOUT) v = v * b2f(FNb[o]) * nmask[m];
                if constexpr (OF32) Cf[o] = v; else Cb[o] = f2b(v);
            }
        }
    }
}

// ---------------------------------------------------------------------------
// LDS staging of WTu1f[128][288] -> sW[128][WPAD] (block-cooperative).
// 288 % 8 == 0 so 8-elem chunks never cross a row.
// ---------------------------------------------------------------------------
__device__ __forceinline__ void stage_wu1f(
    const ushort* __restrict__ WT, ushort* sW)
{
    for (int c = threadIdx.x; c < 128 * 36; c += 256) {
        const int n = c / 36, k = (c % 36) * 8;
        *(s16x8*)(sW + n * WPAD + k) = *(const s16x8*)(WT + n * 288 + k);
    }
    __syncthreads();
}

// ---------------------------------------------------------------------------
// Composed-U1 body, LDS-weight version: out = AF@Wu1a + SATOM@Wc + FBS8@W2c
// Weights re-read from LDS per use (cheap; no L2 latency chain).
// ---------------------------------------------------------------------------
template<bool OF32>
__device__ __forceinline__ void u1f_body(
    int tg, const ushort* __restrict__ AF, const ushort* __restrict__ SATOM,
    const ushort* __restrict__ FBSb, const ushort* sW,
    float* __restrict__ Cf, ushort* __restrict__ Cb)
{
    const int lane = threadIdx.x & 63, wid = threadIdx.x >> 6;
    const int l15 = lane & 15, g = lane >> 4;
    const int wb0 = (2 * wid) * 16 + l15;       // coltile 0 row in sW
    const int wb1 = (2 * wid + 1) * 16 + l15;   // coltile 1 row in sW

    #pragma unroll
    for (int i = 0; i < 4; ++i) {
        const int m0 = (tg * 4 + i) * 16;
        const size_t rb = (size_t)(m0 + l15) * H + g * 8;
        s16x8 ac[9];
        #pragma unroll
        for (int kc = 0; kc < 4; ++kc) {
            ac[kc]     = *(const s16x8*)(AF    + rb + kc * 32);
            ac[kc + 4] = *(const s16x8*)(SATOM + rb + kc * 32);
        }
        ac[8] = (s16x8){0,0,0,0,0,0,0,0};
        if (g == 0) ac[8] = *(const s16x8*)(FBSb + (size_t)(m0 + l15) * 8);

        f32x4 acc[2];
        #pragma unroll
        for (int ct = 0; ct < 2; ++ct) acc[ct] = (f32x4){0.f, 0.f, 0.f, 0.f};
        #pragma unroll
        for (int kc = 0; kc < 9; ++kc) {
            s16x8 w0 = *(const s16x8*)(sW + wb0 * WPAD + kc * 32 + g * 8);
            s16x8 w1 = *(const s16x8*)(sW + wb1 * WPAD + kc * 32 + g * 8);
            acc[0] = __builtin_amdgcn_mfma_f32_16x16x32_bf16(ac[kc], w0, acc[0], 0, 0, 0);
            acc[1] = __builtin_amdgcn_mfma_f32_16x16x32_bf16(ac[kc], w1, acc[1], 0, 0, 0);
        }

        #pragma unroll
        for (int ct = 0; ct < 2; ++ct) {
            const int col = (2 * wid + ct) * 16 + l15;
            #pragma unroll
            for (int r = 0; r < 4; ++r) {
                const size_t o = (size_t)(m0 + 4 * g + r) * H + col;
                if constexpr (OF32) Cf[o] = acc[ct][r]; else Cb[o] = f2b(acc[ct][r]);
            }
        }
    }
}

template<int NC, int FLAGS>
__global__ __launch_bounds__(256, 4) void gemm_af(
    const ushort* __restrict__ Abf, const ushort* __restrict__ WT,
    const ushort* __restrict__ FNb, const float* __restrict__ nmask,
    float* __restrict__ Cf, ushort* __restrict__ Cb)
{
    gemm_body<NC, FLAGS>(swz(blockIdx.x, 128), Abf, WT, FNb, nmask, Cf, Cb);
}

template<bool OF32>
__global__ __launch_bounds__(256, 2) void u1f(
    const ushort* __restrict__ AF, const ushort* __restrict__ SATOM,
    const ushort* __restrict__ FBSb, const ushort* __restrict__ WT,
    float* __restrict__ Cf, ushort* __restrict__ Cb)
{
    __shared__ ushort sW[128 * WPAD];
    stage_wu1f(WT, sW);
    u1f_body<OF32>(swz(blockIdx.x, 128), AF, SATOM, FBSb, sW, Cf, Cb);
}

// final2: [0,1024): atom_features = [AF|SATl|FBS]@WTu1f -> out1 (f32)
//         [1024,2048): kernel = (AF@Wslf)*FNEI*nmask   -> out0 (f32)
__global__ __launch_bounds__(256, 2) void final2(
    const ushort* __restrict__ AF, const ushort* __restrict__ SATl,
    const ushort* __restrict__ FBSb, const ushort* __restrict__ WTu1f,
    const ushort* __restrict__ WTslf, const ushort* __restrict__ FNEIb,
    const float* __restrict__ nmask, float* __restrict__ out1,
    float* __restrict__ out0)
{
    __shared__ ushort sW[128 * WPAD];
    if (blockIdx.x < 1024) {
        stage_wu1f(WTu1f, sW);                   // block-uniform branch: sync ok
        u1f_body<true>(swz(blockIdx.x, 128), AF, SATl, FBSb, sW, out1, nullptr);
    } else {
        gemm_body<4, 8 | 16>(swz(blockIdx.x - 1024, 128), AF, WTslf, FNEIb,
                             nmask, out0, nullptr);
    }
}

// ---------------------------------------------------------------------------
// SATOM gather: SATOM[m][:] = sum_{nb<nnb} AF[b, ag[m,nb]][:]  (bf16)
// ---------------------------------------------------------------------------
__global__ __launch_bounds__(256, 8) void gather_satom(
    const ushort* __restrict__ AF, const int* __restrict__ ag,
    const int* __restrict__ nn, ushort* __restrict__ SATOM)
{
    const int bid = swz(blockIdx.x, 512);
    const int m  = bid * 16 + (threadIdx.x >> 4);
    const int c8 = (threadIdx.x & 15) * 8;
    const int b  = m >> 10;
    const int nnb = nn[m];
    const ushort* AFb = AF + ((size_t)b << 10) * H + c8;
    const int* agm = ag + (size_t)m * NB;

    int2 iv0 = *(const int2*)(agm + 0);
    int2 iv1 = *(const int2*)(agm + 2);
    int2 iv2 = *(const int2*)(agm + 4);
    int2 iv3 = *(const int2*)(agm + 6);
    int2 iv4 = *(const int2*)(agm + 8);

    float sacc[8];
    #pragma unroll
    for (int i = 0; i < 8; ++i) sacc[i] = 0.f;

    #define GS_STEP(nb, ia)                                              \
    if ((nb) < nnb) {                                                    \
        s16x8 av = *(const s16x8*)(AFb + (size_t)(ia) * H);              \
        _Pragma("unroll")                                                \
        for (int i = 0; i < 8; ++i) sacc[i] += b2f((ushort)av[i]);       \
    }
    GS_STEP(0, iv0.x) GS_STEP(1, iv0.y)
    GS_STEP(2, iv1.x) GS_STEP(3, iv1.y)
    GS_STEP(4, iv2.x) GS_STEP(5, iv2.y)
    GS_STEP(6, iv3.x) GS_STEP(7, iv3.y)
    GS_STEP(8, iv4.x) GS_STEP(9, iv4.y)
    #undef GS_STEP

    s16x8 so;
    #pragma unroll
    for (int i = 0; i < 8; ++i) so[i] = (short)f2b(sacc[i]);
    *(s16x8*)(SATOM + (size_t)m * H + c8) = so;
}

// ---------------------------------------------------------------------------
// Last-depth gather: SATOM and FNEI = sum_nb ATW[ag]*HB[bg]  (both bf16 out)
// ---------------------------------------------------------------------------
__global__ __launch_bounds__(256, 4) void gather_last(
    const ushort* __restrict__ AF, const ushort* __restrict__ ATW,
    const ushort* __restrict__ HB, const int* __restrict__ ag,
    const int* __restrict__ bg, const int* __restrict__ nn,
    ushort* __restrict__ SATOM, ushort* __restrict__ FNEIb)
{
    const int bid = swz(blockIdx.x, 512);
    const int m  = bid * 16 + (threadIdx.x >> 4);
    const int c8 = (threadIdx.x & 15) * 8;
    const int b  = m >> 10;
    const int nnb = nn[m];
    const ushort* AFb  = AF  + ((size_t)b << 10) * H + c8;
    const ushort* ATWb = ATW + ((size_t)b << 10) * H + c8;
    const ushort* HBb  = HB  + ((size_t)b << 11) * H + c8;   // E = 2048
    const int* agm = ag + (size_t)m * NB;
    const int* bgm = bg + (size_t)m * NB;

    int2 ia0 = *(const int2*)(agm + 0), ib0 = *(const int2*)(bgm + 0);
    int2 ia1 = *(const int2*)(agm + 2), ib1 = *(const int2*)(bgm + 2);
    int2 ia2 = *(const int2*)(agm + 4), ib2 = *(const int2*)(bgm + 4);
    int2 ia3 = *(const int2*)(agm + 6), ib3 = *(const int2*)(bgm + 6);
    int2 ia4 = *(const int2*)(agm + 8), ib4 = *(const int2*)(bgm + 8);

    float sacc[8], facc[8];
    #pragma unroll
    for (int i = 0; i < 8; ++i) { sacc[i] = 0.f; facc[i] = 0.f; }

    #define GL_STEP(nb, ia, ib)                                          \
    if ((nb) < nnb) {                                                    \
        s16x8 av = *(const s16x8*)(AFb  + (size_t)(ia) * H);             \
        s16x8 tv = *(const s16x8*)(ATWb + (size_t)(ia) * H);             \
        s16x8 hv = *(const s16x8*)(HBb  + (size_t)(ib) * H);             \
        _Pragma("unroll")                                                \
        for (int i = 0; i < 8; ++i) {                                    \
            sacc[i] += b2f((ushort)av[i]);                               \
            facc[i] += b2f((ushort)tv[i]) * b2f((ushort)hv[i]);          \
        }                                                                \
    }
    GL_STEP(0, ia0.x, ib0.x) GL_STEP(1, ia0.y, ib0.y)
    GL_STEP(2, ia1.x, ib1.x) GL_STEP(3, ia1.y, ib1.y)
    GL_STEP(4, ia2.x, ib2.x) GL_STEP(5, ia2.y, ib2.y)
    GL_STEP(6, ia3.x, ib3.x) GL_STEP(7, ia3.y, ib3.y)
    GL_STEP(8, ia4.x, ib4.x) GL_STEP(9, ia4.y, ib4.y)
    #undef GL_STEP

    s16x8 so, fo;
    #pragma unroll
    for (int i = 0; i < 8; ++i) { so[i] = (short)f2b(sacc[i]); fo[i] = (short)f2b(facc[i]); }
    *(s16x8*)(SATOM + (size_t)m * H + c8) = so;
    *(s16x8*)(FNEIb + (size_t)m * H + c8) = fo;
}

// ---------------------------------------------------------------------------
// FA GEMM body reading input_atom f32 directly (K=96 logical, cols>=82 zero)
// ---------------------------------------------------------------------------
__device__ __forceinline__ void fa_body(
    int tg, const float* __restrict__ ia, const float* __restrict__ Wa,
    ushort* __restrict__ Cb)
{
    const int lane = threadIdx.x & 63, wid = threadIdx.x >> 6;
    const int l15 = lane & 15, g = lane >> 4;

    s16x8 w[2][3];
    #pragma unroll
    for (int ct = 0; ct < 2; ++ct) {
        const int n = (2 * wid + ct) * 16 + l15;
        #pragma unroll
        for (int kc = 0; kc < 3; ++kc) {
            s16x8 wv;
            #pragma unroll
            for (int i = 0; i < 8; ++i) {
                const int k = kc * 32 + g * 8 + i;
                wv[i] = (short)(k < 82 ? f2b(Wa[k * H + n]) : 0);
            }
            w[ct][kc] = wv;
        }
    }

    #pragma unroll
    for (int t = 0; t < 4; ++t) {
        const int m0 = (tg * 4 + t) * 16;
        const float* row = ia + (size_t)(m0 + l15) * 82;
        s16x8 a[3];
        #pragma unroll
        for (int kc = 0; kc < 3; ++kc) {
            #pragma unroll
            for (int p = 0; p < 4; ++p) {
                const int k = kc * 32 + g * 8 + 2 * p;     // even; boundary 82 even
                float2 v = (k < 82) ? *(const float2*)(row + k)
                                    : make_float2(0.f, 0.f);
                a[kc][2 * p]     = (short)f2b(v.x);
                a[kc][2 * p + 1] = (short)f2b(v.y);
            }
        }
        f32x4 acc[2];
        #pragma unroll
        for (int ct = 0; ct < 2; ++ct) acc[ct] = (f32x4){0.f, 0.f, 0.f, 0.f};
        #pragma unroll
        for (int kc = 0; kc < 3; ++kc)
            #pragma unroll
            for (int ct = 0; ct < 2; ++ct)
                acc[ct] = __builtin_amdgcn_mfma_f32_16x16x32_bf16(a[kc], w[ct][kc], acc[ct], 0, 0, 0);
        #pragma unroll
        for (int ct = 0; ct < 2; ++ct) {
            const int col = (2 * wid + ct) * 16 + l15;
            #pragma unroll
            for (int r = 0; r < 4; ++r)
                Cb[(size_t)(m0 + 4 * g + r) * H + col] = f2b(acc[ct][r]);
        }
    }
}

// ---------------------------------------------------------------------------
// K0: block-range-split {FA gemm | weights compose | FBS8 | HB}
//  [0,1024): FA  [1024,1296): weights  [1296,1552): FBS  [1552,9744): HB
//  WTs layout: WTna[128][128] | WTslf[128][128] | WTu1f[128][288]
// ---------------------------------------------------------------------------
__global__ __launch_bounds__(256, 4) void k0_prep_fa(
    const float* __restrict__ ia, const float* __restrict__ Wa,
    const float* __restrict__ Wna, const float* __restrict__ Ws,
    const float* __restrict__ Wu2, const float* __restrict__ bu2,
    const float* __restrict__ Wu1, const float* __restrict__ bu1,
    const float* __restrict__ bond, const int* __restrict__ bg,
    const int* __restrict__ nn, const float* __restrict__ Wnb,
    ushort* __restrict__ AF0, ushort* __restrict__ WTs,
    ushort* __restrict__ FBSb, ushort* __restrict__ HB)
{
    const int bid = blockIdx.x;
    if (bid < 1024) {
        fa_body(swz(bid, 128), ia, Wa, AF0);
    } else if (bid < 1296) {
        int t = (bid - 1024) * 256 + threadIdx.x;
        const int tid = t;
        if (t < 128 * 128) { int n = t / 128, k = t % 128;
            WTs[tid] = f2b(Wna[k * H + n]); return; }
        t -= 128 * 128;
        if (t < 128 * 128) { int n = t / 128, k = t % 128;
            WTs[tid] = f2b(Ws[k * H + n]); return; }
        t -= 128 * 128;
        {
            const int n = t / 288, k = t % 288;
            float v = 0.f;
            if (k < 128) {
                v = Wu1[k * H + n];
            } else if (k < 256) {
                const int kk = k - 128;
                float s = 0.f;
                for (int j = 0; j < 128; ++j) s += Wu2[kk * H + j] * Wu1[(128 + j) * H + n];
                v = s;
            } else {
                const int j = k - 256;
                if (j < 6) {
                    float s = 0.f;
                    for (int q = 0; q < 128; ++q) s += Wu2[(128 + j) * H + q] * Wu1[(128 + q) * H + n];
                    v = s;
                } else if (j == 6) {
                    float s = 0.f;
                    for (int q = 0; q < 128; ++q) s += bu2[q] * Wu1[(128 + q) * H + n];
                    v = s;
                } else if (j == 7) {
                    v = bu1[n];
                }
            }
            WTs[tid] = f2b(v);
            return;
        }
    } else if (bid < 1552) {
        // FBS8[m][8] = bf16[ sum_nb bond[bg[m,nb]][0..5], num_nbs, 1 ]
        const int m = (bid - 1296) * 256 + threadIdx.x;
        const int b = m >> 10;
        const int nnb = nn[m];
        float s[6] = {0,0,0,0,0,0};
        for (int nb = 0; nb < nnb; ++nb) {
            const int ib = bg[m * NB + nb];
            const float* fb = bond + ((size_t)(b << 11) + (size_t)ib) * 6;
            #pragma unroll
            for (int j = 0; j < 6; ++j) s[j] += fb[j];
        }
        s16x8 o;
        #pragma unroll
        for (int j = 0; j < 6; ++j) o[j] = (short)f2b(s[j]);
        o[6] = (short)f2b((float)nnb);
        o[7] = (short)f2b(1.0f);
        *(s16x8*)(FBSb + (size_t)m * 8) = o;
    } else {
        // HB[b][e][:] = bond[b,e,:] @ W_nei_bond  (bf16)
        const int t = (bid - 1552) * 256 + threadIdx.x;    // B*E*16
        const int r = t >> 4, c8 = (t & 15) * 8;
        const float* fb = bond + (size_t)r * 6;
        const float2 f01 = *(const float2*)fb;
        const float2 f23 = *(const float2*)(fb + 2);
        const float2 f45 = *(const float2*)(fb + 4);
        s16x8 o;
        #pragma unroll
        for (int i = 0; i < 8; ++i) {
            const int c = c8 + i;
            const float v = f01.x * Wnb[0 * H + c] + f01.y * Wnb[1 * H + c]
                          + f23.x * Wnb[2 * H + c] + f23.y * Wnb[3 * H + c]
                          + f45.x * Wnb[4 * H + c] + f45.y * Wnb[5 * H + c];
            o[i] = (short)f2b(v);
        }
        *(s16x8*)(HB + (size_t)r * H + c8) = o;
    }
}

// ---------------------------------------------------------------------------
extern "C" void kernel_launch(void* const* d_in, const int* in_sizes, int n_in,
                              void* d_out, int out_size, void* d_ws, size_t ws_size,
                              hipStream_t stream)
{
    (void)in_sizes; (void)n_in; (void)out_size; (void)ws_size;

    const float* input_atom = (const float*)d_in[0];
    const float* input_bond = (const float*)d_in[1];
    const int*   atom_graph = (const int*)d_in[2];
    const int*   bond_graph = (const int*)d_in[3];
    const int*   num_nbs    = (const int*)d_in[4];
    const float* node_mask  = (const float*)d_in[5];
    const float* W_atom     = (const float*)d_in[6];
    const float* W_nei_atom = (const float*)d_in[7];
    const float* W_nei_bond = (const float*)d_in[8];
    const float* W_self     = (const float*)d_in[9];
    const float* W_U2       = (const float*)d_in[10];
    const float* b_U2       = (const float*)d_in[11];
    const float* W_U1       = (const float*)d_in[12];
    const float* b_U1       = (const float*)d_in[13];

    char* ws = (char*)d_ws;
    const size_t MB = 1024 * 1024;
    ushort* AF0   = (ushort*)(ws);               // [0,16) MB
    ushort* AF1   = (ushort*)(ws + 16 * MB);     // [16,32) MB (FNEI at last depth)
    ushort* SATw  = (ushort*)(ws + 32 * MB);     // [32,48) MB (ATW at last depth)
    ushort* ATW   = SATw;
    ushort* HB    = (ushort*)(ws + 64 * MB);     // [64,96) MB
    ushort* SATl  = (ushort*)(ws + 96 * MB);     // [96,112) MB
    ushort* FBSb  = (ushort*)(ws + 112 * MB);    // 1 MB
    ushort* WTs_  = (ushort*)(ws + 113 * MB);    // ~140 KB

    ushort* WTna  = WTs_;                        // [128][128]
    ushort* WTslf = WTna  + 128 * 128;           // [128][128]
    ushort* WTu1f = WTslf + 128 * 128;           // [128][288]

    float*  out0  = (float*)d_out;               // kernel [M][128] f32
    float*  out1  = out0 + SL;                   // atom_features [M][128] f32
    ushort* FNEIb = AF1;                         // last-depth FNEI scratch

    // K0: FA gemm || weights compose || FBS || HB
    k0_prep_fa<<<9744, 256, 0, stream>>>(input_atom, W_atom, W_nei_atom,
                                         W_self, W_U2, b_U2, W_U1, b_U1,
                                         input_bond, bond_graph, num_nbs,
                                         W_nei_bond, AF0, WTs_, FBSb, HB);

    // depth 0
    gather_satom<<<4096, 256, 0, stream>>>(AF0, atom_graph, num_nbs, SATw);
    u1f<false><<<1024, 256, 0, stream>>>(AF0, SATw, FBSb, WTu1f, nullptr, AF1);
    // depth 1
    gather_satom<<<4096, 256, 0, stream>>>(AF1, atom_graph, num_nbs, SATw);
    u1f<false><<<1024, 256, 0, stream>>>(AF1, SATw, FBSb, WTu1f, nullptr, AF0);

    // ---- last depth (AF = AF0; AF1 dead -> FNEI scratch; SATw -> ATW) ----
    gemm_af<4, 0><<<1024, 256, 0, stream>>>(AF0, WTna, nullptr, nullptr,
                                            nullptr, ATW);
    gather_last<<<4096, 256, 0, stream>>>(AF0, ATW, HB, atom_graph, bond_graph,
                                          num_nbs, SATl, FNEIb);
    // atom_features -> out1 (f32)  ||  kernel -> out0 (f32)
    final2<<<2048, 256, 0, stream>>>(AF0, SATl, FBSb, WTu1f, WTslf, FNEIb,
                                     node_mask, out1, out0);
}

// Round 13
// 185.469 us; speedup vs baseline: 1.2301x; 1.0910x over previous
//
#include <hip/hip_runtime.h>

constexpr int NB = 10, H = 128;
constexpr int M = 64 * 1024;             // B*A rows
constexpr long SL = (long)M * H;         // elems per [M,H] matrix

typedef __attribute__((ext_vector_type(8))) short s16x8;
typedef __attribute__((ext_vector_type(4))) float f32x4;

__device__ __forceinline__ ushort f2b(float f) {
    union { float f; uint u; } v; v.f = f;
    uint u = v.u;
    uint r = u + 0x7fffu + ((u >> 16) & 1u);
    return (ushort)(r >> 16);
}
__device__ __forceinline__ float b2f(ushort u) {
    union { uint u; float f; } v; v.u = ((uint)u) << 16; return v.f;
}

// XCD-chunked bijective swizzle (sub-grid % 8 == 0)
__device__ __forceinline__ int swz(int bid, int cpx) {
    return (bid & 7) * cpx + (bid >> 3);
}

// ---------------------------------------------------------------------------
// GEMM body (K<=128): wave owns 32 cols, w[2][NC]<=32 VGPR — resident at the
// 64-reg tier (verified R8: VGPR=64, best-measured).  FLAGS: 8=KOUT, 16=OF32
// ---------------------------------------------------------------------------
template<int NC, int FLAGS>
__device__ __forceinline__ void gemm_body(
    int tg, const ushort* __restrict__ Abf, const ushort* __restrict__ WT,
    const ushort* __restrict__ FNb, const float* __restrict__ nmask,
    float* __restrict__ Cf, ushort* __restrict__ Cb)
{
    constexpr bool KOUT = FLAGS & 8, OF32 = FLAGS & 16;
    constexpr int K = NC * 32;
    const int lane = threadIdx.x & 63, wid = threadIdx.x >> 6;
    const int l15 = lane & 15, g = lane >> 4;

    s16x8 w[2][NC];
    #pragma unroll
    for (int ct = 0; ct < 2; ++ct)
        #pragma unroll
        for (int kc = 0; kc < NC; ++kc)
            w[ct][kc] = *(const s16x8*)(WT + (size_t)((2 * wid + ct) * 16 + l15) * K + kc * 32 + g * 8);

    #pragma unroll
    for (int i = 0; i < 4; ++i) {
        const int m0 = (tg * 4 + i) * 16;
        s16x8 ac[NC];
        #pragma unroll
        for (int kc = 0; kc < NC; ++kc)
            ac[kc] = *(const s16x8*)(Abf + (size_t)(m0 + l15) * K + kc * 32 + g * 8);

        f32x4 acc[2];
        #pragma unroll
        for (int ct = 0; ct < 2; ++ct) acc[ct] = (f32x4){0.f, 0.f, 0.f, 0.f};
        #pragma unroll
        for (int kc = 0; kc < NC; ++kc)
            #pragma unroll
            for (int ct = 0; ct < 2; ++ct)
                acc[ct] = __builtin_amdgcn_mfma_f32_16x16x32_bf16(ac[kc], w[ct][kc], acc[ct], 0, 0, 0);

        #pragma unroll
        for (int ct = 0; ct < 2; ++ct) {
            const int col = (2 * wid + ct) * 16 + l15;
            #pragma unroll
            for (int r = 0; r < 4; ++r) {
                const int m = m0 + 4 * g + r;
                const size_t o = (size_t)m * H + col;
                float v = acc[ct][r];
                if constexpr (KOUT) v = v * b2f(FNb[o]) * nmask[m];
                if constexpr (OF32) Cf[o] = v; else Cb[o] = f2b(v);
            }
        }
    }
}

// ---------------------------------------------------------------------------
// Composed-U1 body: out = AF@Wu1a + SATOM@Wc + FBS8@W2c   (K=288, 9 chunks)
// Weight fragments PINNED via opaque asm so the compiler cannot rematerialize
// the 18 L2 loads inside the row-tile loop (R8/R10/R11 showed it always does
// otherwise — the 5%-MfmaUtil latency chain).
// ---------------------------------------------------------------------------
template<bool OF32>
__device__ __forceinline__ void u1f_body(
    int tg, const ushort* __restrict__ AF, const ushort* __restrict__ SATOM,
    const ushort* __restrict__ FBSb, const ushort* __restrict__ WT,
    float* __restrict__ Cf, ushort* __restrict__ Cb)
{
    const int lane = threadIdx.x & 63, wid = threadIdx.x >> 6;
    const int l15 = lane & 15, g = lane >> 4;

    s16x8 w[2][9];
    #pragma unroll
    for (int ct = 0; ct < 2; ++ct)
        #pragma unroll
        for (int kc = 0; kc < 9; ++kc)
            w[ct][kc] = *(const s16x8*)(WT + (size_t)((2 * wid + ct) * 16 + l15) * 288 + kc * 32 + g * 8);
    // opaque def: keeps all 72 weight VGPRs live, forbids remat
    #pragma unroll
    for (int ct = 0; ct < 2; ++ct)
        #pragma unroll
        for (int kc = 0; kc < 9; ++kc)
            asm volatile("" : "+v"(w[ct][kc]));

    #pragma unroll
    for (int i = 0; i < 4; ++i) {
        const int m0 = (tg * 4 + i) * 16;
        const size_t rb = (size_t)(m0 + l15) * H + g * 8;
        s16x8 ac[9];
        #pragma unroll
        for (int kc = 0; kc < 4; ++kc) {
            ac[kc]     = *(const s16x8*)(AF    + rb + kc * 32);
            ac[kc + 4] = *(const s16x8*)(SATOM + rb + kc * 32);
        }
        ac[8] = (s16x8){0,0,0,0,0,0,0,0};
        if (g == 0) ac[8] = *(const s16x8*)(FBSb + (size_t)(m0 + l15) * 8);

        f32x4 acc[2];
        #pragma unroll
        for (int ct = 0; ct < 2; ++ct) acc[ct] = (f32x4){0.f, 0.f, 0.f, 0.f};
        #pragma unroll
        for (int kc = 0; kc < 9; ++kc)
            #pragma unroll
            for (int ct = 0; ct < 2; ++ct)
                acc[ct] = __builtin_amdgcn_mfma_f32_16x16x32_bf16(ac[kc], w[ct][kc], acc[ct], 0, 0, 0);

        #pragma unroll
        for (int ct = 0; ct < 2; ++ct) {
            const int col = (2 * wid + ct) * 16 + l15;
            #pragma unroll
            for (int r = 0; r < 4; ++r) {
                const size_t o = (size_t)(m0 + 4 * g + r) * H + col;
                if constexpr (OF32) Cf[o] = acc[ct][r]; else Cb[o] = f2b(acc[ct][r]);
            }
        }
    }
}

template<int NC, int FLAGS>
__global__ __launch_bounds__(256, 4) void gemm_af(
    const ushort* __restrict__ Abf, const ushort* __restrict__ WT,
    const ushort* __restrict__ FNb, const float* __restrict__ nmask,
    float* __restrict__ Cf, ushort* __restrict__ Cb)
{
    gemm_body<NC, FLAGS>(swz(blockIdx.x, 128), Abf, WT, FNb, nmask, Cf, Cb);
}

template<bool OF32>
__global__ __launch_bounds__(256, 3) void u1f(
    const ushort* __restrict__ AF, const ushort* __restrict__ SATOM,
    const ushort* __restrict__ FBSb, const ushort* __restrict__ WT,
    float* __restrict__ Cf, ushort* __restrict__ Cb)
{
    u1f_body<OF32>(swz(blockIdx.x, 128), AF, SATOM, FBSb, WT, Cf, Cb);
}

// final2: [0,1024): atom_features = [AF|SATl|FBS]@WTu1f -> out1 (f32)
//         [1024,2048): kernel = (AF@Wslf)*FNEI*nmask   -> out0 (f32)
__global__ __launch_bounds__(256, 3) void final2(
    const ushort* __restrict__ AF, const ushort* __restrict__ SATl,
    const ushort* __restrict__ FBSb, const ushort* __restrict__ WTu1f,
    const ushort* __restrict__ WTslf, const ushort* __restrict__ FNEIb,
    const float* __restrict__ nmask, float* __restrict__ out1,
    float* __restrict__ out0)
{
    if (blockIdx.x < 1024)
        u1f_body<true>(swz(blockIdx.x, 128), AF, SATl, FBSb, WTu1f, out1, nullptr);
    else
        gemm_body<4, 8 | 16>(swz(blockIdx.x - 1024, 128), AF, WTslf, FNEIb,
                             nmask, out0, nullptr);
}

// ---------------------------------------------------------------------------
// SATOM gather: SATOM[m][:] = sum_{nb<nnb} AF[b, ag[m,nb]][:]  (bf16)
// ---------------------------------------------------------------------------
__global__ __launch_bounds__(256, 8) void gather_satom(
    const ushort* __restrict__ AF, const int* __restrict__ ag,
    const int* __restrict__ nn, ushort* __restrict__ SATOM)
{
    const int bid = swz(blockIdx.x, 512);
    const int m  = bid * 16 + (threadIdx.x >> 4);
    const int c8 = (threadIdx.x & 15) * 8;
    const int b  = m >> 10;
    const int nnb = nn[m];
    const ushort* AFb = AF + ((size_t)b << 10) * H + c8;
    const int* agm = ag + (size_t)m * NB;

    int2 iv0 = *(const int2*)(agm + 0);
    int2 iv1 = *(const int2*)(agm + 2);
    int2 iv2 = *(const int2*)(agm + 4);
    int2 iv3 = *(const int2*)(agm + 6);
    int2 iv4 = *(const int2*)(agm + 8);

    float sacc[8];
    #pragma unroll
    for (int i = 0; i < 8; ++i) sacc[i] = 0.f;

    #define GS_STEP(nb, ia)                                              \
    if ((nb) < nnb) {                                                    \
        s16x8 av = *(const s16x8*)(AFb + (size_t)(ia) * H);              \
        _Pragma("unroll")                                                \
        for (int i = 0; i < 8; ++i) sacc[i] += b2f((ushort)av[i]);       \
    }
    GS_STEP(0, iv0.x) GS_STEP(1, iv0.y)
    GS_STEP(2, iv1.x) GS_STEP(3, iv1.y)
    GS_STEP(4, iv2.x) GS_STEP(5, iv2.y)
    GS_STEP(6, iv3.x) GS_STEP(7, iv3.y)
    GS_STEP(8, iv4.x) GS_STEP(9, iv4.y)
    #undef GS_STEP

    s16x8 so;
    #pragma unroll
    for (int i = 0; i < 8; ++i) so[i] = (short)f2b(sacc[i]);
    *(s16x8*)(SATOM + (size_t)m * H + c8) = so;
}

// ---------------------------------------------------------------------------
// Last-depth gather: SATOM and FNEI = sum_nb ATW[ag]*HB[bg]  (both bf16 out)
// ---------------------------------------------------------------------------
__global__ __launch_bounds__(256, 4) void gather_last(
    const ushort* __restrict__ AF, const ushort* __restrict__ ATW,
    const ushort* __restrict__ HB, const int* __restrict__ ag,
    const int* __restrict__ bg, const int* __restrict__ nn,
    ushort* __restrict__ SATOM, ushort* __restrict__ FNEIb)
{
    const int bid = swz(blockIdx.x, 512);
    const int m  = bid * 16 + (threadIdx.x >> 4);
    const int c8 = (threadIdx.x & 15) * 8;
    const int b  = m >> 10;
    const int nnb = nn[m];
    const ushort* AFb  = AF  + ((size_t)b << 10) * H + c8;
    const ushort* ATWb = ATW + ((size_t)b << 10) * H + c8;
    const ushort* HBb  = HB  + ((size_t)b << 11) * H + c8;   // E = 2048
    const int* agm = ag + (size_t)m * NB;
    const int* bgm = bg + (size_t)m * NB;

    int2 ia0 = *(const int2*)(agm + 0), ib0 = *(const int2*)(bgm + 0);
    int2 ia1 = *(const int2*)(agm + 2), ib1 = *(const int2*)(bgm + 2);
    int2 ia2 = *(const int2*)(agm + 4), ib2 = *(const int2*)(bgm + 4);
    int2 ia3 = *(const int2*)(agm + 6), ib3 = *(const int2*)(bgm + 6);
    int2 ia4 = *(const int2*)(agm + 8), ib4 = *(const int2*)(bgm + 8);

    float sacc[8], facc[8];
    #pragma unroll
    for (int i = 0; i < 8; ++i) { sacc[i] = 0.f; facc[i] = 0.f; }

    #define GL_STEP(nb, ia, ib)                                          \
    if ((nb) < nnb) {                                                    \
        s16x8 av = *(const s16x8*)(AFb  + (size_t)(ia) * H);             \
        s16x8 tv = *(const s16x8*)(ATWb + (size_t)(ia) * H);             \
        s16x8 hv = *(const s16x8*)(HBb  + (size_t)(ib) * H);             \
        _Pragma("unroll")                                                \
        for (int i = 0; i < 8; ++i) {                                    \
            sacc[i] += b2f((ushort)av[i]);                               \
            facc[i] += b2f((ushort)tv[i]) * b2f((ushort)hv[i]);          \
        }                                                                \
    }
    GL_STEP(0, ia0.x, ib0.x) GL_STEP(1, ia0.y, ib0.y)
    GL_STEP(2, ia1.x, ib1.x) GL_STEP(3, ia1.y, ib1.y)
    GL_STEP(4, ia2.x, ib2.x) GL_STEP(5, ia2.y, ib2.y)
    GL_STEP(6, ia3.x, ib3.x) GL_STEP(7, ia3.y, ib3.y)
    GL_STEP(8, ia4.x, ib4.x) GL_STEP(9, ia4.y, ib4.y)
    #undef GL_STEP

    s16x8 so, fo;
    #pragma unroll
    for (int i = 0; i < 8; ++i) { so[i] = (short)f2b(sacc[i]); fo[i] = (short)f2b(facc[i]); }
    *(s16x8*)(SATOM + (size_t)m * H + c8) = so;
    *(s16x8*)(FNEIb + (size_t)m * H + c8) = fo;
}

// ---------------------------------------------------------------------------
// FA GEMM body reading input_atom f32 directly (K=96 logical, cols>=82 zero)
// ---------------------------------------------------------------------------
__device__ __forceinline__ void fa_body(
    int tg, const float* __restrict__ ia, const float* __restrict__ Wa,
    ushort* __restrict__ Cb)
{
    const int lane = threadIdx.x & 63, wid = threadIdx.x >> 6;
    const int l15 = lane & 15, g = lane >> 4;

    s16x8 w[2][3];
    #pragma unroll
    for (int ct = 0; ct < 2; ++ct) {
        const int n = (2 * wid + ct) * 16 + l15;
        #pragma unroll
        for (int kc = 0; kc < 3; ++kc) {
            s16x8 wv;
            #pragma unroll
            for (int i = 0; i < 8; ++i) {
                const int k = kc * 32 + g * 8 + i;
                wv[i] = (short)(k < 82 ? f2b(Wa[k * H + n]) : 0);
            }
            w[ct][kc] = wv;
        }
    }

    #pragma unroll
    for (int t = 0; t < 4; ++t) {
        const int m0 = (tg * 4 + t) * 16;
        const float* row = ia + (size_t)(m0 + l15) * 82;
        s16x8 a[3];
        #pragma unroll
        for (int kc = 0; kc < 3; ++kc) {
            #pragma unroll
            for (int p = 0; p < 4; ++p) {
                const int k = kc * 32 + g * 8 + 2 * p;     // even; boundary 82 even
                float2 v = (k < 82) ? *(const float2*)(row + k)
                                    : make_float2(0.f, 0.f);
                a[kc][2 * p]     = (short)f2b(v.x);
                a[kc][2 * p + 1] = (short)f2b(v.y);
            }
        }
        f32x4 acc[2];
        #pragma unroll
        for (int ct = 0; ct < 2; ++ct) acc[ct] = (f32x4){0.f, 0.f, 0.f, 0.f};
        #pragma unroll
        for (int kc = 0; kc < 3; ++kc)
            #pragma unroll
            for (int ct = 0; ct < 2; ++ct)
                acc[ct] = __builtin_amdgcn_mfma_f32_16x16x32_bf16(a[kc], w[ct][kc], acc[ct], 0, 0, 0);
        #pragma unroll
        for (int ct = 0; ct < 2; ++ct) {
            const int col = (2 * wid + ct) * 16 + l15;
            #pragma unroll
            for (int r = 0; r < 4; ++r)
                Cb[(size_t)(m0 + 4 * g + r) * H + col] = f2b(acc[ct][r]);
        }
    }
}

// ---------------------------------------------------------------------------
// K0: block-range-split {FA gemm | weights compose | FBS8 | HB}
//  [0,1024): FA  [1024,1296): weights  [1296,1552): FBS  [1552,9744): HB
//  WTs layout: WTna[128][128] | WTslf[128][128] | WTu1f[128][288]
// ---------------------------------------------------------------------------
__global__ __launch_bounds__(256, 4) void k0_prep_fa(
    const float* __restrict__ ia, const float* __restrict__ Wa,
    const float* __restrict__ Wna, const float* __restrict__ Ws,
    const float* __restrict__ Wu2, const float* __restrict__ bu2,
    const float* __restrict__ Wu1, const float* __restrict__ bu1,
    const float* __restrict__ bond, const int* __restrict__ bg,
    const int* __restrict__ nn, const float* __restrict__ Wnb,
    ushort* __restrict__ AF0, ushort* __restrict__ WTs,
    ushort* __restrict__ FBSb, ushort* __restrict__ HB)
{
    const int bid = blockIdx.x;
    if (bid < 1024) {
        fa_body(swz(bid, 128), ia, Wa, AF0);
    } else if (bid < 1296) {
        int t = (bid - 1024) * 256 + threadIdx.x;
        const int tid = t;
        if (t < 128 * 128) { int n = t / 128, k = t % 128;
            WTs[tid] = f2b(Wna[k * H + n]); return; }
        t -= 128 * 128;
        if (t < 128 * 128) { int n = t / 128, k = t % 128;
            WTs[tid] = f2b(Ws[k * H + n]); return; }
        t -= 128 * 128;
        {
            const int n = t / 288, k = t % 288;
            float v = 0.f;
            if (k < 128) {
                v = Wu1[k * H + n];
            } else if (k < 256) {
                const int kk = k - 128;
                float s = 0.f;
                for (int j = 0; j < 128; ++j) s += Wu2[kk * H + j] * Wu1[(128 + j) * H + n];
                v = s;
            } else {
                const int j = k - 256;
                if (j < 6) {
                    float s = 0.f;
                    for (int q = 0; q < 128; ++q) s += Wu2[(128 + j) * H + q] * Wu1[(128 + q) * H + n];
                    v = s;
                } else if (j == 6) {
                    float s = 0.f;
                    for (int q = 0; q < 128; ++q) s += bu2[q] * Wu1[(128 + q) * H + n];
                    v = s;
                } else if (j == 7) {
                    v = bu1[n];
                }
            }
            WTs[tid] = f2b(v);
            return;
        }
    } else if (bid < 1552) {
        // FBS8[m][8] = bf16[ sum_nb bond[bg[m,nb]][0..5], num_nbs, 1 ]
        const int m = (bid - 1296) * 256 + threadIdx.x;
        const int b = m >> 10;
        const int nnb = nn[m];
        float s[6] = {0,0,0,0,0,0};
        for (int nb = 0; nb < nnb; ++nb) {
            const int ib = bg[m * NB + nb];
            const float* fb = bond + ((size_t)(b << 11) + (size_t)ib) * 6;
            #pragma unroll
            for (int j = 0; j < 6; ++j) s[j] += fb[j];
        }
        s16x8 o;
        #pragma unroll
        for (int j = 0; j < 6; ++j) o[j] = (short)f2b(s[j]);
        o[6] = (short)f2b((float)nnb);
        o[7] = (short)f2b(1.0f);
        *(s16x8*)(FBSb + (size_t)m * 8) = o;
    } else {
        // HB[b][e][:] = bond[b,e,:] @ W_nei_bond  (bf16)
        const int t = (bid - 1552) * 256 + threadIdx.x;    // B*E*16
        const int r = t >> 4, c8 = (t & 15) * 8;
        const float* fb = bond + (size_t)r * 6;
        const float2 f01 = *(const float2*)fb;
        const float2 f23 = *(const float2*)(fb + 2);
        const float2 f45 = *(const float2*)(fb + 4);
        s16x8 o;
        #pragma unroll
        for (int i = 0; i < 8; ++i) {
            const int c = c8 + i;
            const float v = f01.x * Wnb[0 * H + c] + f01.y * Wnb[1 * H + c]
                          + f23.x * Wnb[2 * H + c] + f23.y * Wnb[3 * H + c]
                          + f45.x * Wnb[4 * H + c] + f45.y * Wnb[5 * H + c];
            o[i] = (short)f2b(v);
        }
        *(s16x8*)(HB + (size_t)r * H + c8) = o;
    }
}

// ---------------------------------------------------------------------------
extern "C" void kernel_launch(void* const* d_in, const int* in_sizes, int n_in,
                              void* d_out, int out_size, void* d_ws, size_t ws_size,
                              hipStream_t stream)
{
    (void)in_sizes; (void)n_in; (void)out_size; (void)ws_size;

    const float* input_atom = (const float*)d_in[0];
    const float* input_bond = (const float*)d_in[1];
    const int*   atom_graph = (const int*)d_in[2];
    const int*   bond_graph = (const int*)d_in[3];
    const int*   num_nbs    = (const int*)d_in[4];
    const float* node_mask  = (const float*)d_in[5];
    const float* W_atom     = (const float*)d_in[6];
    const float* W_nei_atom = (const float*)d_in[7];
    const float* W_nei_bond = (const float*)d_in[8];
    const float* W_self     = (const float*)d_in[9];
    const float* W_U2       = (const float*)d_in[10];
    const float* b_U2       = (const float*)d_in[11];
    const float* W_U1       = (const float*)d_in[12];
    const float* b_U1       = (const float*)d_in[13];

    char* ws = (char*)d_ws;
    const size_t MB = 1024 * 1024;
    ushort* AF0   = (ushort*)(ws);               // [0,16) MB
    ushort* AF1   = (ushort*)(ws + 16 * MB);     // [16,32) MB (FNEI at last depth)
    ushort* SATw  = (ushort*)(ws + 32 * MB);     // [32,48) MB (ATW at last depth)
    ushort* ATW   = SATw;
    ushort* HB    = (ushort*)(ws + 64 * MB);     // [64,96) MB
    ushort* SATl  = (ushort*)(ws + 96 * MB);     // [96,112) MB
    ushort* FBSb  = (ushort*)(ws + 112 * MB);    // 1 MB
    ushort* WTs_  = (ushort*)(ws + 113 * MB);    // ~140 KB

    ushort* WTna  = WTs_;                        // [128][128]
    ushort* WTslf = WTna  + 128 * 128;           // [128][128]
    ushort* WTu1f = WTslf + 128 * 128;           // [128][288]

    float*  out0  = (float*)d_out;               // kernel [M][128] f32
    float*  out1  = out0 + SL;                   // atom_features [M][128] f32
    ushort* FNEIb = AF1;                         // last-depth FNEI scratch

    // K0: FA gemm || weights compose || FBS || HB
    k0_prep_fa<<<9744, 256, 0, stream>>>(input_atom, W_atom, W_nei_atom,
                                         W_self, W_U2, b_U2, W_U1, b_U1,
                                         input_bond, bond_graph, num_nbs,
                                         W_nei_bond, AF0, WTs_, FBSb, HB);

    // depth 0
    gather_satom<<<4096, 256, 0, stream>>>(AF0, atom_graph, num_nbs, SATw);
    u1f<false><<<1024, 256, 0, stream>>>(AF0, SATw, FBSb, WTu1f, nullptr, AF1);
    // depth 1
    gather_satom<<<4096, 256, 0, stream>>>(AF1, atom_graph, num_nbs, SATw);
    u1f<false><<<1024, 256, 0, stream>>>(AF1, SATw, FBSb, WTu1f, nullptr, AF0);

    // ---- last depth (AF = AF0; AF1 dead -> FNEI scratch; SATw -> ATW) ----
    gemm_af<4, 0><<<1024, 256, 0, stream>>>(AF0, WTna, nullptr, nullptr,
                                            nullptr, ATW);
    gather_last<<<4096, 256, 0, stream>>>(AF0, ATW, HB, atom_graph, bond_graph,
                                          num_nbs, SATl, FNEIb);
    // atom_features -> out1 (f32)  ||  kernel -> out0 (f32)
    final2<<<2048, 256, 0, stream>>>(AF0, SATl, FBSb, WTu1f, WTslf, FNEIb,
                                     node_mask, out1, out0);
}